// Round 5
// baseline (1766.977 us; speedup 1.0000x reference)
//
#include <hip/hip_runtime.h>

static constexpr int TPB = 256;
static constexpr int SD  = 21;   // state dim
static constexpr int HD  = 64;   // hidden
static constexpr int LT  = 14;   // latent

__device__ __forceinline__ float frcp(float x){ return __builtin_amdgcn_rcpf(x); }
__device__ __forceinline__ float frsq(float x){ return __builtin_amdgcn_rsqf(x); }

__device__ __forceinline__ float ftanh(float x){
    x = fminf(15.0f, fmaxf(-15.0f, x));
    float e = __expf(2.0f * x);
    return (e - 1.0f) * frcp(e + 1.0f);
}

template<int N>
__device__ __forceinline__ void softmax_scale(float (&v)[N], float gate){
    float mx = v[0];
#pragma unroll
    for (int j = 1; j < N; ++j) mx = fmaxf(mx, v[j]);
    float s = 0.0f;
#pragma unroll
    for (int j = 0; j < N; ++j){ v[j] = __expf(v[j] - mx); s += v[j]; }
    float r = frcp(s) * gate;
#pragma unroll
    for (int j = 0; j < N; ++j) v[j] *= r;
}

// accumulate acc[0:4] += x * w4
__device__ __forceinline__ void fma4(float* acc, float x, float4 w){
    acc[0] = fmaf(x, w.x, acc[0]);
    acc[1] = fmaf(x, w.y, acc[1]);
    acc[2] = fmaf(x, w.z, acc[2]);
    acc[3] = fmaf(x, w.w, acc[3]);
}

__global__ __launch_bounds__(TPB, 6) void statenet_v5_kernel(
    const float* __restrict__ state,
    const float* __restrict__ W1,  const float* __restrict__ b1,
    const float* __restrict__ lng, const float* __restrict__ lnb,
    const float* __restrict__ W2,  const float* __restrict__ b2,
    const float* __restrict__ W3,  const float* __restrict__ b3,
    const float* __restrict__ Wd1, const float* __restrict__ bd1,
    const float* __restrict__ Wd2, const float* __restrict__ bd2,
    const float* __restrict__ Wm,  const float* __restrict__ bm,
    const float* __restrict__ Wh,  const float* __restrict__ bh,
    const float* __restrict__ Wc,  const float* __restrict__ bc,
    const float* __restrict__ psm, const float* __restrict__ psh,
    const float* __restrict__ psc,
    float* __restrict__ out, int N)
{
    __shared__ float srow[TPB * SD];     // 21504 B -> 7 blocks/CU max by LDS
    const int tid = threadIdx.x;
    const long long row0 = (long long)blockIdx.x * TPB;

    // coalesced stage: 256 rows (21504 B) via float4 (block base is 16B aligned)
    {
        const float4* g  = reinterpret_cast<const float4*>(state + row0 * SD);
        float4*       s4 = reinterpret_cast<float4*>(srow);
        constexpr int NV = TPB * SD / 4;  // 1344
#pragma unroll
        for (int i = 0; i < 6; ++i) {
            int idx = tid + i * TPB;
            if (idx < NV) s4[idx] = g[idx];
        }
    }
    __syncthreads();

    // per-thread row read: stride 21 floats (odd) -> free 2-way bank aliasing
    float ns[SD];
#pragma unroll
    for (int k = 0; k < SD; ++k) ns[k] = srow[tid * SD + k];

    // _normalize
    ns[0]  *= (1.0f / 3.0f);
    ns[1]  *= (1.0f / 3.0f);
    ns[17] *= 0.5f;
    ns[18] *= 0.25f;
    ns[19]  = fminf(fmaxf(ns[19], 0.0f), 2.0f) * 0.5f;

    // ---- attention heads (k-outer; small rows stay scalar) ----
    float m[13], hv[6], cv[4];
#pragma unroll
    for (int j = 0; j < 13; ++j) m[j]  = bm[j];
#pragma unroll
    for (int j = 0; j < 6;  ++j) hv[j] = bh[j];
    {
        float4 b4 = reinterpret_cast<const float4*>(bc)[0];
        cv[0] = b4.x; cv[1] = b4.y; cv[2] = b4.z; cv[3] = b4.w;
    }
#pragma unroll
    for (int k = 0; k < SD; ++k) {
        float x = ns[k];
#pragma unroll
        for (int j = 0; j < 13; ++j) m[j]  = fmaf(x, Wm[k * 13 + j], m[j]);
#pragma unroll
        for (int j = 0; j < 6;  ++j) hv[j] = fmaf(x, Wh[k * 6 + j], hv[j]);
#pragma unroll
        for (int j = 0; j < 4;  ++j) cv[j] = fmaf(x, Wc[k * 4 + j], cv[j]);
    }
    const float gm = 2.0f * frcp(1.0f + __expf(-psm[0]));
    const float gh = 2.0f * frcp(1.0f + __expf(-psh[0]));
    const float gc = 2.0f * frcp(1.0f + __expf(-psc[0]));
    softmax_scale<13>(m,  gm);
    softmax_scale<6 >(hv, gh);
    softmax_scale<4 >(cv, gc);

    const long long row = row0 + tid;

    // store metric / hyp / curr now (frees registers for the MLP)
    {
        float* pm = out + (long long)22 * N + row * 13;
#pragma unroll
        for (int j = 0; j < 13; ++j) pm[j] = m[j];
        float* ph = out + (long long)35 * N + row * 6;   // 8B aligned
#pragma unroll
        for (int j = 0; j < 3; ++j)
            reinterpret_cast<float2*>(ph)[j] = make_float2(hv[2 * j], hv[2 * j + 1]);
        float* pc = out + (long long)41 * N + row * 4;   // 16B aligned
        reinterpret_cast<float4*>(pc)[0] = make_float4(cv[0], cv[1], cv[2], cv[3]);
    }

    // attended = ns * metric[EXPAND_IDX]
    constexpr int EIDX[SD] = {0,1,2,3,4,4,5,5,5,6,6,6,7,7,8,9,9,10,10,11,12};
    float at[SD];
#pragma unroll
    for (int k = 0; k < SD; ++k) at[k] = ns[k] * m[EIDX[k]];

    // enc1: [21] @ [21x64]  (rows are 256B-stride -> float4)
    float h[HD];
#pragma unroll
    for (int j4 = 0; j4 < HD / 4; ++j4) {
        float4 b4 = reinterpret_cast<const float4*>(b1)[j4];
        h[4*j4+0] = b4.x; h[4*j4+1] = b4.y; h[4*j4+2] = b4.z; h[4*j4+3] = b4.w;
    }
#pragma unroll
    for (int k = 0; k < SD; ++k) {
        float x = at[k];
        const float4* wr = reinterpret_cast<const float4*>(W1 + k * HD);
#pragma unroll
        for (int j4 = 0; j4 < HD / 4; ++j4) fma4(&h[4*j4], x, wr[j4]);
    }

    // layernorm + tanh
    float mu = 0.0f;
#pragma unroll
    for (int j = 0; j < HD; ++j) mu += h[j];
    mu *= (1.0f / HD);
    float var = 0.0f;
#pragma unroll
    for (int j = 0; j < HD; ++j) { float d = h[j] - mu; var = fmaf(d, d, var); }
    var *= (1.0f / HD);
    float istd = frsq(var + 1e-5f);
#pragma unroll
    for (int j = 0; j < HD; ++j)
        h[j] = ftanh(fmaf((h[j] - mu) * istd, lng[j], lnb[j]));

    // enc2: [64] @ [64x64] + relu   (float4 weight rows)
    float h2[HD];
#pragma unroll
    for (int j4 = 0; j4 < HD / 4; ++j4) {
        float4 b4 = reinterpret_cast<const float4*>(b2)[j4];
        h2[4*j4+0] = b4.x; h2[4*j4+1] = b4.y; h2[4*j4+2] = b4.z; h2[4*j4+3] = b4.w;
    }
#pragma unroll
    for (int k = 0; k < HD; ++k) {
        float x = h[k];
        const float4* wr = reinterpret_cast<const float4*>(W2 + k * HD);
#pragma unroll
        for (int j4 = 0; j4 < HD / 4; ++j4) fma4(&h2[4*j4], x, wr[j4]);
    }
#pragma unroll
    for (int j = 0; j < HD; ++j) h2[j] = fmaxf(h2[j], 0.0f);

    // enc3 -> latent [14]   (rows are 56B-stride -> float2)
    float lat[LT];
#pragma unroll
    for (int j2 = 0; j2 < LT / 2; ++j2) {
        float2 b2v = reinterpret_cast<const float2*>(b3)[j2];
        lat[2*j2+0] = b2v.x; lat[2*j2+1] = b2v.y;
    }
#pragma unroll
    for (int k = 0; k < HD; ++k) {
        float x = h2[k];
        const float2* wr = reinterpret_cast<const float2*>(W3 + k * LT);
#pragma unroll
        for (int j2 = 0; j2 < LT / 2; ++j2) {
            float2 w = wr[j2];
            lat[2*j2+0] = fmaf(x, w.x, lat[2*j2+0]);
            lat[2*j2+1] = fmaf(x, w.y, lat[2*j2+1]);
        }
    }
    {
        float* pl = out + (long long)8 * N + row * 14;   // 8B aligned
#pragma unroll
        for (int j = 0; j < 7; ++j)
            reinterpret_cast<float2*>(pl)[j] = make_float2(lat[2 * j], lat[2 * j + 1]);
    }

    // dec1: [14] @ [14x64] + relu   (float4 weight rows)
    float d1[HD];
#pragma unroll
    for (int j4 = 0; j4 < HD / 4; ++j4) {
        float4 b4 = reinterpret_cast<const float4*>(bd1)[j4];
        d1[4*j4+0] = b4.x; d1[4*j4+1] = b4.y; d1[4*j4+2] = b4.z; d1[4*j4+3] = b4.w;
    }
#pragma unroll
    for (int k = 0; k < LT; ++k) {
        float x = lat[k];
        const float4* wr = reinterpret_cast<const float4*>(Wd1 + k * HD);
#pragma unroll
        for (int j4 = 0; j4 < HD / 4; ++j4) fma4(&d1[4*j4], x, wr[j4]);
    }
#pragma unroll
    for (int j = 0; j < HD; ++j) d1[j] = fmaxf(d1[j], 0.0f);

    // dec2 -> corrections [8], tanh   (rows are 32B-stride -> float4)
    float c8[8];
#pragma unroll
    for (int j4 = 0; j4 < 2; ++j4) {
        float4 b4 = reinterpret_cast<const float4*>(bd2)[j4];
        c8[4*j4+0] = b4.x; c8[4*j4+1] = b4.y; c8[4*j4+2] = b4.z; c8[4*j4+3] = b4.w;
    }
#pragma unroll
    for (int k = 0; k < HD; ++k) {
        float x = d1[k];
        const float4* wr = reinterpret_cast<const float4*>(Wd2 + k * 8);
        fma4(&c8[0], x, wr[0]);
        fma4(&c8[4], x, wr[1]);
    }
    {
        float* pc = out + row * 8;                       // 16B aligned
        reinterpret_cast<float4*>(pc)[0] =
            make_float4(ftanh(c8[0]), ftanh(c8[1]), ftanh(c8[2]), ftanh(c8[3]));
        reinterpret_cast<float4*>(pc)[1] =
            make_float4(ftanh(c8[4]), ftanh(c8[5]), ftanh(c8[6]), ftanh(c8[7]));
    }
}

extern "C" void kernel_launch(void* const* d_in, const int* in_sizes, int n_in,
                              void* d_out, int out_size, void* d_ws, size_t ws_size,
                              hipStream_t stream)
{
    const float* state = (const float*)d_in[0];
    const float* W1   = (const float*)d_in[1];
    const float* b1   = (const float*)d_in[2];
    const float* lng  = (const float*)d_in[3];
    const float* lnb  = (const float*)d_in[4];
    const float* W2   = (const float*)d_in[5];
    const float* b2   = (const float*)d_in[6];
    const float* W3   = (const float*)d_in[7];
    const float* b3   = (const float*)d_in[8];
    const float* Wd1  = (const float*)d_in[9];
    const float* bd1  = (const float*)d_in[10];
    const float* Wd2  = (const float*)d_in[11];
    const float* bd2  = (const float*)d_in[12];
    const float* Wm   = (const float*)d_in[13];
    const float* bm   = (const float*)d_in[14];
    const float* Wh   = (const float*)d_in[15];
    const float* bh   = (const float*)d_in[16];
    const float* Wc   = (const float*)d_in[17];
    const float* bc   = (const float*)d_in[18];
    const float* psm  = (const float*)d_in[19];
    const float* psh  = (const float*)d_in[20];
    const float* psc  = (const float*)d_in[21];

    const int N = in_sizes[0] / SD;          // 1048576
    dim3 grid((N + TPB - 1) / TPB), block(TPB);
    hipLaunchKernelGGL(statenet_v5_kernel, grid, block, 0, stream,
                       state, W1, b1, lng, lnb, W2, b2, W3, b3,
                       Wd1, bd1, Wd2, bd2, Wm, bm, Wh, bh, Wc, bc,
                       psm, psh, psc, (float*)d_out, N);
}

// Round 6
// 303.494 us; speedup vs baseline: 5.8221x; 5.8221x over previous
//
#include <hip/hip_runtime.h>

static constexpr int TPB = 256;
static constexpr int SD  = 21;   // state dim
static constexpr int HD  = 64;   // hidden
static constexpr int LT  = 14;   // latent

__device__ __forceinline__ float frcp(float x){ return __builtin_amdgcn_rcpf(x); }
__device__ __forceinline__ float frsq(float x){ return __builtin_amdgcn_rsqf(x); }

__device__ __forceinline__ float ftanh(float x){
    x = fminf(15.0f, fmaxf(-15.0f, x));
    float e = __expf(2.0f * x);
    return (e - 1.0f) * frcp(e + 1.0f);
}

template<int N>
__device__ __forceinline__ void softmax_scale(float (&v)[N], float gate){
    float mx = v[0];
#pragma unroll
    for (int j = 1; j < N; ++j) mx = fmaxf(mx, v[j]);
    float s = 0.0f;
#pragma unroll
    for (int j = 0; j < N; ++j){ v[j] = __expf(v[j] - mx); s += v[j]; }
    float r = frcp(s) * gate;
#pragma unroll
    for (int j = 0; j < N; ++j) v[j] *= r;
}

__global__ __launch_bounds__(TPB, 4) void statenet_v5_kernel(
    const float* __restrict__ state,
    const float* __restrict__ W1,  const float* __restrict__ b1,
    const float* __restrict__ lng, const float* __restrict__ lnb,
    const float* __restrict__ W2,  const float* __restrict__ b2,
    const float* __restrict__ W3,  const float* __restrict__ b3,
    const float* __restrict__ Wd1, const float* __restrict__ bd1,
    const float* __restrict__ Wd2, const float* __restrict__ bd2,
    const float* __restrict__ Wm,  const float* __restrict__ bm,
    const float* __restrict__ Wh,  const float* __restrict__ bh,
    const float* __restrict__ Wc,  const float* __restrict__ bc,
    const float* __restrict__ psm, const float* __restrict__ psh,
    const float* __restrict__ psc,
    float* __restrict__ out, int N)
{
    const int tid = threadIdx.x;
    const long long row = (long long)blockIdx.x * TPB + tid;

    // direct per-thread row read: 21 dword loads, one-time; input stream is
    // consumed exactly once per wave window -> L1/L2 absorb the 84B-stride.
    // (No LDS, no __syncthreads: waves fully independent; LDS_Block_Size=0
    //  removes any LDS-based occupancy cap — this round's experiment.)
    float ns[SD];
    {
        const float* p = state + row * SD;
#pragma unroll
        for (int k = 0; k < SD; ++k) ns[k] = p[k];
    }

    // _normalize
    ns[0]  *= (1.0f / 3.0f);
    ns[1]  *= (1.0f / 3.0f);
    ns[17] *= 0.5f;
    ns[18] *= 0.25f;
    ns[19]  = fminf(fmaxf(ns[19], 0.0f), 2.0f) * 0.5f;

    // ---- attention heads (k-outer so weight rows are contiguous/uniform -> s_load) ----
    float m[13], hv[6], cv[4];
#pragma unroll
    for (int j = 0; j < 13; ++j) m[j]  = bm[j];
#pragma unroll
    for (int j = 0; j < 6;  ++j) hv[j] = bh[j];
#pragma unroll
    for (int j = 0; j < 4;  ++j) cv[j] = bc[j];
#pragma unroll
    for (int k = 0; k < SD; ++k) {
        float x = ns[k];
#pragma unroll
        for (int j = 0; j < 13; ++j) m[j]  = fmaf(x, Wm[k * 13 + j], m[j]);
#pragma unroll
        for (int j = 0; j < 6;  ++j) hv[j] = fmaf(x, Wh[k * 6 + j], hv[j]);
#pragma unroll
        for (int j = 0; j < 4;  ++j) cv[j] = fmaf(x, Wc[k * 4 + j], cv[j]);
    }
    const float gm = 2.0f * frcp(1.0f + __expf(-psm[0]));
    const float gh = 2.0f * frcp(1.0f + __expf(-psh[0]));
    const float gc = 2.0f * frcp(1.0f + __expf(-psc[0]));
    softmax_scale<13>(m,  gm);
    softmax_scale<6 >(hv, gh);
    softmax_scale<4 >(cv, cv ? gc : gc);

    // store metric / hyp / curr now (frees registers for the MLP)
    {
        float* pm = out + (long long)22 * N + row * 13;
#pragma unroll
        for (int j = 0; j < 13; ++j) pm[j] = m[j];
        float* ph = out + (long long)35 * N + row * 6;   // 8B aligned
#pragma unroll
        for (int j = 0; j < 3; ++j)
            reinterpret_cast<float2*>(ph)[j] = make_float2(hv[2 * j], hv[2 * j + 1]);
        float* pc = out + (long long)41 * N + row * 4;   // 16B aligned
        reinterpret_cast<float4*>(pc)[0] = make_float4(cv[0], cv[1], cv[2], cv[3]);
    }

    // attended = ns * metric[EXPAND_IDX]
    constexpr int EIDX[SD] = {0,1,2,3,4,4,5,5,5,6,6,6,7,7,8,9,9,10,10,11,12};
    float at[SD];
#pragma unroll
    for (int k = 0; k < SD; ++k) at[k] = ns[k] * m[EIDX[k]];

    // enc1: [21] @ [21x64]
    float h[HD];
#pragma unroll
    for (int j = 0; j < HD; ++j) h[j] = b1[j];
#pragma unroll
    for (int k = 0; k < SD; ++k) {
        float x = at[k];
#pragma unroll
        for (int j = 0; j < HD; ++j) h[j] = fmaf(x, W1[k * HD + j], h[j]);
    }

    // layernorm + tanh
    float mu = 0.0f;
#pragma unroll
    for (int j = 0; j < HD; ++j) mu += h[j];
    mu *= (1.0f / HD);
    float var = 0.0f;
#pragma unroll
    for (int j = 0; j < HD; ++j) { float d = h[j] - mu; var = fmaf(d, d, var); }
    var *= (1.0f / HD);
    float istd = frsq(var + 1e-5f);
#pragma unroll
    for (int j = 0; j < HD; ++j)
        h[j] = ftanh(fmaf((h[j] - mu) * istd, lng[j], lnb[j]));

    // enc2: [64] @ [64x64] + relu
    float h2[HD];
#pragma unroll
    for (int j = 0; j < HD; ++j) h2[j] = b2[j];
#pragma unroll
    for (int k = 0; k < HD; ++k) {
        float x = h[k];
#pragma unroll
        for (int j = 0; j < HD; ++j) h2[j] = fmaf(x, W2[k * HD + j], h2[j]);
    }
#pragma unroll
    for (int j = 0; j < HD; ++j) h2[j] = fmaxf(h2[j], 0.0f);

    // enc3 -> latent [14]
    float lat[LT];
#pragma unroll
    for (int j = 0; j < LT; ++j) lat[j] = b3[j];
#pragma unroll
    for (int k = 0; k < HD; ++k) {
        float x = h2[k];
#pragma unroll
        for (int j = 0; j < LT; ++j) lat[j] = fmaf(x, W3[k * LT + j], lat[j]);
    }
    {
        float* pl = out + (long long)8 * N + row * 14;   // 8B aligned
#pragma unroll
        for (int j = 0; j < 7; ++j)
            reinterpret_cast<float2*>(pl)[j] = make_float2(lat[2 * j], lat[2 * j + 1]);
    }

    // dec1: [14] @ [14x64] + relu
    float d1[HD];
#pragma unroll
    for (int j = 0; j < HD; ++j) d1[j] = bd1[j];
#pragma unroll
    for (int k = 0; k < LT; ++k) {
        float x = lat[k];
#pragma unroll
        for (int j = 0; j < HD; ++j) d1[j] = fmaf(x, Wd1[k * HD + j], d1[j]);
    }
#pragma unroll
    for (int j = 0; j < HD; ++j) d1[j] = fmaxf(d1[j], 0.0f);

    // dec2 -> corrections [8], tanh
    float c8[8];
#pragma unroll
    for (int j = 0; j < 8; ++j) c8[j] = bd2[j];
#pragma unroll
    for (int k = 0; k < HD; ++k) {
        float x = d1[k];
#pragma unroll
        for (int j = 0; j < 8; ++j) c8[j] = fmaf(x, Wd2[k * 8 + j], c8[j]);
    }
    {
        float* pc = out + row * 8;                       // 16B aligned
        reinterpret_cast<float4*>(pc)[0] =
            make_float4(ftanh(c8[0]), ftanh(c8[1]), ftanh(c8[2]), ftanh(c8[3]));
        reinterpret_cast<float4*>(pc)[1] =
            make_float4(ftanh(c8[4]), ftanh(c8[5]), ftanh(c8[6]), ftanh(c8[7]));
    }
}

extern "C" void kernel_launch(void* const* d_in, const int* in_sizes, int n_in,
                              void* d_out, int out_size, void* d_ws, size_t ws_size,
                              hipStream_t stream)
{
    const float* state = (const float*)d_in[0];
    const float* W1   = (const float*)d_in[1];
    const float* b1   = (const float*)d_in[2];
    const float* lng  = (const float*)d_in[3];
    const float* lnb  = (const float*)d_in[4];
    const float* W2   = (const float*)d_in[5];
    const float* b2   = (const float*)d_in[6];
    const float* W3   = (const float*)d_in[7];
    const float* b3   = (const float*)d_in[8];
    const float* Wd1  = (const float*)d_in[9];
    const float* bd1  = (const float*)d_in[10];
    const float* Wd2  = (const float*)d_in[11];
    const float* bd2  = (const float*)d_in[12];
    const float* Wm   = (const float*)d_in[13];
    const float* bm   = (const float*)d_in[14];
    const float* Wh   = (const float*)d_in[15];
    const float* bh   = (const float*)d_in[16];
    const float* Wc   = (const float*)d_in[17];
    const float* bc   = (const float*)d_in[18];
    const float* psm  = (const float*)d_in[19];
    const float* psh  = (const float*)d_in[20];
    const float* psc  = (const float*)d_in[21];

    const int N = in_sizes[0] / SD;          // 1048576
    dim3 grid((N + TPB - 1) / TPB), block(TPB);
    hipLaunchKernelGGL(statenet_v5_kernel, grid, block, 0, stream,
                       state, W1, b1, lng, lnb, W2, b2, W3, b3,
                       Wd1, bd1, Wd2, bd2, Wm, bm, Wh, bh, Wc, bc,
                       psm, psh, psc, (float*)d_out, N);
}

// Round 8
// 222.218 us; speedup vs baseline: 7.9515x; 1.3657x over previous
//
#include <hip/hip_runtime.h>

static constexpr int TPB = 256;
static constexpr int SD  = 21;   // state dim
static constexpr int HD  = 64;   // hidden
static constexpr int LT  = 14;   // latent

// packed-weight layout in d_ws (u32 = 2×f16 along K; "lo"=even k, "hi"=odd k)
static constexpr int P1_OFF = 0;              // enc1: [11][64]  (k=21 padded to 22)
static constexpr int P2_OFF = 704;            // enc2: [32][64]
static constexpr int P3_OFF = 2752;           // enc3: [32][14]
static constexpr int PD1_OFF = 3200;          // dec1: [7][64]
static constexpr int PD2_OFF = 3648;          // dec2: [32][8]
static constexpr int PTOT   = 3904;           // u32 elements

typedef _Float16 h2_t  __attribute__((ext_vector_type(2)));  // fdot2 operand type
typedef __fp16   pk_t  __attribute__((ext_vector_type(2)));  // cvt_pkrtz result type

__device__ __forceinline__ float frcp(float x){ return __builtin_amdgcn_rcpf(x); }
__device__ __forceinline__ float frsq(float x){ return __builtin_amdgcn_rsqf(x); }

__device__ __forceinline__ unsigned packrtz(float a, float b){
    pk_t h = __builtin_amdgcn_cvt_pkrtz(a, b);   // v_cvt_pkrtz_f16_f32
    union { pk_t h; unsigned u; } u; u.h = h; return u.u;
}

// acc += dot(xp, wp) with f16 multiply, f32 accumulate (v_dot2_f32_f16)
__device__ __forceinline__ float dot2(unsigned xp, unsigned wp, float acc){
    union { unsigned u; h2_t h; } a, b; a.u = xp; b.u = wp;
    return __builtin_amdgcn_fdot2(a.h, b.h, acc, false);
}

__device__ __forceinline__ float ftanh(float x){
    x = fminf(15.0f, fmaxf(-15.0f, x));
    float e = __expf(2.0f * x);
    return (e - 1.0f) * frcp(e + 1.0f);
}

template<int N>
__device__ __forceinline__ void softmax_scale(float (&v)[N], float gate){
    float mx = v[0];
#pragma unroll
    for (int j = 1; j < N; ++j) mx = fmaxf(mx, v[j]);
    float s = 0.0f;
#pragma unroll
    for (int j = 0; j < N; ++j){ v[j] = __expf(v[j] - mx); s += v[j]; }
    float r = frcp(s) * gate;
#pragma unroll
    for (int j = 0; j < N; ++j) v[j] *= r;
}

// ---- prep: pack W[K][J] f32 -> u32(f16 pair along K) into d_ws ----
__global__ void pack_weights_kernel(const float* __restrict__ W1,
                                    const float* __restrict__ W2,
                                    const float* __restrict__ W3,
                                    const float* __restrict__ Wd1,
                                    const float* __restrict__ Wd2,
                                    unsigned* __restrict__ ws)
{
    int idx = blockIdx.x * blockDim.x + threadIdx.x;
    if (idx >= PTOT) return;
    float a, b;
    if (idx < P2_OFF) {                       // P1: [11][64] from W1[21][64]
        int e = idx - P1_OFF, kk = e >> 6, j = e & 63;
        a = W1[(2*kk)*HD + j];
        b = (2*kk + 1 < SD) ? W1[(2*kk+1)*HD + j] : 0.0f;
    } else if (idx < P3_OFF) {                // P2: [32][64] from W2[64][64]
        int e = idx - P2_OFF, kk = e >> 6, j = e & 63;
        a = W2[(2*kk)*HD + j];
        b = W2[(2*kk+1)*HD + j];
    } else if (idx < PD1_OFF) {               // P3: [32][14] from W3[64][14]
        int e = idx - P3_OFF, kk = e / LT, j = e % LT;
        a = W3[(2*kk)*LT + j];
        b = W3[(2*kk+1)*LT + j];
    } else if (idx < PD2_OFF) {               // Pd1: [7][64] from Wd1[14][64]
        int e = idx - PD1_OFF, kk = e >> 6, j = e & 63;
        a = Wd1[(2*kk)*HD + j];
        b = Wd1[(2*kk+1)*HD + j];
    } else {                                  // Pd2: [32][8] from Wd2[64][8]
        int e = idx - PD2_OFF, kk = e >> 3, j = e & 7;
        a = Wd2[(2*kk)*8 + j];
        b = Wd2[(2*kk+1)*8 + j];
    }
    ws[idx] = packrtz(a, b);
}

__global__ __launch_bounds__(TPB, 4) void statenet_v5_kernel(
    const float* __restrict__ state,
    const unsigned* __restrict__ pw,          // packed weights in ws
    const float* __restrict__ b1,
    const float* __restrict__ lng, const float* __restrict__ lnb,
    const float* __restrict__ b2,  const float* __restrict__ b3,
    const float* __restrict__ bd1, const float* __restrict__ bd2,
    const float* __restrict__ Wm,  const float* __restrict__ bm,
    const float* __restrict__ Wh,  const float* __restrict__ bh,
    const float* __restrict__ Wc,  const float* __restrict__ bc,
    const float* __restrict__ psm, const float* __restrict__ psh,
    const float* __restrict__ psc,
    float* __restrict__ out, int N)
{
    const int tid = threadIdx.x;
    const long long row = (long long)blockIdx.x * TPB + tid;

    // direct per-thread row read (R6-validated: no LDS, no barriers)
    float ns[SD];
    {
        const float* p = state + row * SD;
#pragma unroll
        for (int k = 0; k < SD; ++k) ns[k] = p[k];
    }

    // _normalize
    ns[0]  *= (1.0f / 3.0f);
    ns[1]  *= (1.0f / 3.0f);
    ns[17] *= 0.5f;
    ns[18] *= 0.25f;
    ns[19]  = fminf(fmaxf(ns[19], 0.0f), 2.0f) * 0.5f;

    // ---- attention heads: fp32 (precision-sensitive, only 483 FMAs) ----
    float m[13], hv[6], cv[4];
#pragma unroll
    for (int j = 0; j < 13; ++j) m[j]  = bm[j];
#pragma unroll
    for (int j = 0; j < 6;  ++j) hv[j] = bh[j];
#pragma unroll
    for (int j = 0; j < 4;  ++j) cv[j] = bc[j];
#pragma unroll
    for (int k = 0; k < SD; ++k) {
        float x = ns[k];
#pragma unroll
        for (int j = 0; j < 13; ++j) m[j]  = fmaf(x, Wm[k * 13 + j], m[j]);
#pragma unroll
        for (int j = 0; j < 6;  ++j) hv[j] = fmaf(x, Wh[k * 6 + j], hv[j]);
#pragma unroll
        for (int j = 0; j < 4;  ++j) cv[j] = fmaf(x, Wc[k * 4 + j], cv[j]);
    }
    const float gm = 2.0f * frcp(1.0f + __expf(-psm[0]));
    const float gh = 2.0f * frcp(1.0f + __expf(-psh[0]));
    const float gc = 2.0f * frcp(1.0f + __expf(-psc[0]));
    softmax_scale<13>(m,  gm);
    softmax_scale<6 >(hv, gh);
    softmax_scale<4 >(cv, gc);

    // store metric / hyp / curr
    {
        float* pm = out + (long long)22 * N + row * 13;
#pragma unroll
        for (int j = 0; j < 13; ++j) pm[j] = m[j];
        float* ph = out + (long long)35 * N + row * 6;   // 8B aligned
#pragma unroll
        for (int j = 0; j < 3; ++j)
            reinterpret_cast<float2*>(ph)[j] = make_float2(hv[2 * j], hv[2 * j + 1]);
        float* pc = out + (long long)41 * N + row * 4;   // 16B aligned
        reinterpret_cast<float4*>(pc)[0] = make_float4(cv[0], cv[1], cv[2], cv[3]);
    }

    // attended = ns * metric[EXPAND_IDX], packed to f16 pairs (k=21 -> 11 pairs)
    constexpr int EIDX[SD] = {0,1,2,3,4,4,5,5,5,6,6,6,7,7,8,9,9,10,10,11,12};
    float at[SD];
#pragma unroll
    for (int k = 0; k < SD; ++k) at[k] = ns[k] * m[EIDX[k]];
    unsigned atp[11];
#pragma unroll
    for (int kk = 0; kk < 10; ++kk) atp[kk] = packrtz(at[2*kk], at[2*kk+1]);
    atp[10] = packrtz(at[20], 0.0f);

    // enc1: [21] @ [21x64] via dot2
    float h[HD];
#pragma unroll
    for (int j = 0; j < HD; ++j) h[j] = b1[j];
#pragma unroll
    for (int kk = 0; kk < 11; ++kk) {
        unsigned x = atp[kk];
        const unsigned* wr = pw + P1_OFF + kk * HD;
#pragma unroll
        for (int j = 0; j < HD; ++j) h[j] = dot2(x, wr[j], h[j]);
    }

    // layernorm + tanh (fp32)
    float mu = 0.0f;
#pragma unroll
    for (int j = 0; j < HD; ++j) mu += h[j];
    mu *= (1.0f / HD);
    float var = 0.0f;
#pragma unroll
    for (int j = 0; j < HD; ++j) { float d = h[j] - mu; var = fmaf(d, d, var); }
    var *= (1.0f / HD);
    float istd = frsq(var + 1e-5f);
#pragma unroll
    for (int j = 0; j < HD; ++j)
        h[j] = ftanh(fmaf((h[j] - mu) * istd, lng[j], lnb[j]));

    // pack h -> 32 pairs (h dies after this)
    unsigned hp[32];
#pragma unroll
    for (int kk = 0; kk < 32; ++kk) hp[kk] = packrtz(h[2*kk], h[2*kk+1]);

    // enc2: [64] @ [64x64] + relu via dot2
    float h2[HD];
#pragma unroll
    for (int j = 0; j < HD; ++j) h2[j] = b2[j];
#pragma unroll
    for (int kk = 0; kk < 32; ++kk) {
        unsigned x = hp[kk];
        const unsigned* wr = pw + P2_OFF + kk * HD;
#pragma unroll
        for (int j = 0; j < HD; ++j) h2[j] = dot2(x, wr[j], h2[j]);
    }
#pragma unroll
    for (int j = 0; j < HD; ++j) h2[j] = fmaxf(h2[j], 0.0f);

    // pack h2 -> 32 pairs (h2 dies)
    unsigned h2p[32];
#pragma unroll
    for (int kk = 0; kk < 32; ++kk) h2p[kk] = packrtz(h2[2*kk], h2[2*kk+1]);

    // enc3 -> latent [14] via dot2
    float lat[LT];
#pragma unroll
    for (int j = 0; j < LT; ++j) lat[j] = b3[j];
#pragma unroll
    for (int kk = 0; kk < 32; ++kk) {
        unsigned x = h2p[kk];
        const unsigned* wr = pw + P3_OFF + kk * LT;
#pragma unroll
        for (int j = 0; j < LT; ++j) lat[j] = dot2(x, wr[j], lat[j]);
    }
    {
        float* pl = out + (long long)8 * N + row * 14;   // 8B aligned
#pragma unroll
        for (int j = 0; j < 7; ++j)
            reinterpret_cast<float2*>(pl)[j] = make_float2(lat[2 * j], lat[2 * j + 1]);
    }

    // dec1: [14] @ [14x64] + relu via dot2
    unsigned latp[7];
#pragma unroll
    for (int kk = 0; kk < 7; ++kk) latp[kk] = packrtz(lat[2*kk], lat[2*kk+1]);
    float d1[HD];
#pragma unroll
    for (int j = 0; j < HD; ++j) d1[j] = bd1[j];
#pragma unroll
    for (int kk = 0; kk < 7; ++kk) {
        unsigned x = latp[kk];
        const unsigned* wr = pw + PD1_OFF + kk * HD;
#pragma unroll
        for (int j = 0; j < HD; ++j) d1[j] = dot2(x, wr[j], d1[j]);
    }
#pragma unroll
    for (int j = 0; j < HD; ++j) d1[j] = fmaxf(d1[j], 0.0f);

    // dec2 -> corrections [8], tanh, via dot2
    unsigned d1p[32];
#pragma unroll
    for (int kk = 0; kk < 32; ++kk) d1p[kk] = packrtz(d1[2*kk], d1[2*kk+1]);
    float c8[8];
#pragma unroll
    for (int j = 0; j < 8; ++j) c8[j] = bd2[j];
#pragma unroll
    for (int kk = 0; kk < 32; ++kk) {
        unsigned x = d1p[kk];
        const unsigned* wr = pw + PD2_OFF + kk * 8;
#pragma unroll
        for (int j = 0; j < 8; ++j) c8[j] = dot2(x, wr[j], c8[j]);
    }
    {
        float* pc = out + row * 8;                       // 16B aligned
        reinterpret_cast<float4*>(pc)[0] =
            make_float4(ftanh(c8[0]), ftanh(c8[1]), ftanh(c8[2]), ftanh(c8[3]));
        reinterpret_cast<float4*>(pc)[1] =
            make_float4(ftanh(c8[4]), ftanh(c8[5]), ftanh(c8[6]), ftanh(c8[7]));
    }
}

extern "C" void kernel_launch(void* const* d_in, const int* in_sizes, int n_in,
                              void* d_out, int out_size, void* d_ws, size_t ws_size,
                              hipStream_t stream)
{
    const float* state = (const float*)d_in[0];
    const float* W1   = (const float*)d_in[1];
    const float* b1   = (const float*)d_in[2];
    const float* lng  = (const float*)d_in[3];
    const float* lnb  = (const float*)d_in[4];
    const float* W2   = (const float*)d_in[5];
    const float* b2   = (const float*)d_in[6];
    const float* W3   = (const float*)d_in[7];
    const float* b3   = (const float*)d_in[8];
    const float* Wd1  = (const float*)d_in[9];
    const float* bd1  = (const float*)d_in[10];
    const float* Wd2  = (const float*)d_in[11];
    const float* bd2  = (const float*)d_in[12];
    const float* Wm   = (const float*)d_in[13];
    const float* bm   = (const float*)d_in[14];
    const float* Wh   = (const float*)d_in[15];
    const float* bh   = (const float*)d_in[16];
    const float* Wc   = (const float*)d_in[17];
    const float* bc   = (const float*)d_in[18];
    const float* psm  = (const float*)d_in[19];
    const float* psh  = (const float*)d_in[20];
    const float* psc  = (const float*)d_in[21];

    unsigned* pw = (unsigned*)d_ws;

    // pack weights to f16 pairs (3904 u32; 16 blocks)
    hipLaunchKernelGGL(pack_weights_kernel, dim3((PTOT + 255) / 256), dim3(256),
                       0, stream, W1, W2, W3, Wd1, Wd2, pw);

    const int N = in_sizes[0] / SD;          // 1048576
    dim3 grid((N + TPB - 1) / TPB), block(TPB);
    hipLaunchKernelGGL(statenet_v5_kernel, grid, block, 0, stream,
                       state, pw, b1, lng, lnb, b2, b3, bd1, bd2,
                       Wm, bm, Wh, bh, Wc, bc,
                       psm, psh, psc, (float*)d_out, N);
}